// Round 6
// baseline (476.757 us; speedup 1.0000x reference)
//
#include <hip/hip_runtime.h>
#include <stdint.h>

typedef __bf16 bf16;
typedef __bf16 bf16x8 __attribute__((ext_vector_type(8)));
typedef __bf16 bf16x4 __attribute__((ext_vector_type(4)));
typedef float  f32x4  __attribute__((ext_vector_type(4)));

#define T_SEQ  2048
#define NHEAD  16
#define DHEAD  128
#define DMODEL 2048
#define NQKV   3072   // 2048 Q | 512 K | 512 V per row
#define UNROLL _Pragma("unroll")

__device__ __forceinline__ void gload_lds16(const void* g, void* l) {
  __builtin_amdgcn_global_load_lds(
      (const __attribute__((address_space(1))) uint32_t*)g,
      (__attribute__((address_space(3))) uint32_t*)l, 16, 0, 0);
}

// ---------------- fp32 -> bf16 cast (x) ----------------
__global__ void k_cvt(const float* __restrict__ in, bf16* __restrict__ out) {
  int i = (blockIdx.x * 256 + threadIdx.x) * 4;
  float4 v = *(const float4*)(in + i);
  bf16x4 o = { (bf16)v.x, (bf16)v.y, (bf16)v.z, (bf16)v.w };
  *(bf16x4*)(out + i) = o;
}

// ---------------- W (K x N fp32) -> WT (N x K bf16) ----------------
__global__ __launch_bounds__(256) void k_twt(const float* __restrict__ W,
                                             bf16* __restrict__ WT, int K, int N) {
  __shared__ float t[64][65];
  int k0 = blockIdx.x * 64, n0 = blockIdx.y * 64;
  int r4 = threadIdx.x >> 6, c = threadIdx.x & 63;
#pragma unroll
  for (int i = 0; i < 16; i++) {
    int r = i * 4 + r4;
    t[r][c] = W[(size_t)(k0 + r) * N + n0 + c];
  }
  __syncthreads();
#pragma unroll
  for (int i = 0; i < 16; i++) {
    int r = i * 4 + r4;
    WT[(size_t)(n0 + r) * K + k0 + c] = (bf16)t[c][r];
  }
}

// ---------------- V pre-transpose: QKV V-cols -> Vtg[(b*4+kvh)*128 + d][t] ----
__global__ __launch_bounds__(256) void k_vt(const bf16* __restrict__ QKV,
                                            bf16* __restrict__ Vtg) {
  __shared__ bf16 t[64][65];
  const int t0 = blockIdx.x * 64, d0 = blockIdx.y * 64;
  const int g = blockIdx.z, b = g >> 2, kvh = g & 3;
  const bf16* src = QKV + (size_t)b * T_SEQ * NQKV + 2560 + kvh * DHEAD;
  bf16* dst = Vtg + ((size_t)(b * 4 + kvh) * 128 + d0) * T_SEQ + t0;
  const int r4 = threadIdx.x >> 6, c = threadIdx.x & 63;
#pragma unroll
  for (int i = 0; i < 16; i++) {
    int r = i * 4 + r4;
    t[r][c] = src[(size_t)(t0 + r) * NQKV + d0 + c];
  }
  __syncthreads();
#pragma unroll
  for (int i = 0; i < 16; i++) {
    int r = i * 4 + r4;
    dst[(size_t)r * T_SEQ + c] = t[c][r];
  }
}

// ---------------- GEMM: C[M,N] = A[M,K] * BT[N,K]^T  (m97 + XCD swizzle) --------
template<bool F32OUT>
__global__ __launch_bounds__(256) void k_gemm(const bf16* __restrict__ A,
                                              const bf16* __restrict__ BT,
                                              void* __restrict__ C,
                                              int M, int N, int K) {
  __shared__ __align__(16) bf16 As[128 * 64];
  __shared__ __align__(16) bf16 Bs[128 * 64];
  const int nwg = gridDim.x * gridDim.y;
  const int orig = blockIdx.y * gridDim.x + blockIdx.x;
  const int tile = (orig & 7) * (nwg >> 3) + (orig >> 3);   // nwg % 8 == 0
  const int m0 = (tile % gridDim.x) * 128, n0 = (tile / gridDim.x) * 128;
  const int tid = threadIdx.x;
  const int lane = tid & 63, w = tid >> 6;
  const int wr = w >> 1, wc = w & 1;
  const int l15 = lane & 15, lg = lane >> 4;
  f32x4 acc[4][4] = {};

  const int rA = w * 32 + (lane >> 3);
  const int cA = (lane & 7) * 8;
  const bf16* gA = A  + (size_t)(m0 + rA) * K + cA;
  const bf16* gB = BT + (size_t)(n0 + rA) * K + cA;

  for (int k0 = 0; k0 < K; k0 += 64) {
    __syncthreads();
#pragma unroll
    for (int i = 0; i < 4; i++) {
      gload_lds16(gA + (size_t)i * 8 * K + k0, As + (w * 4 + i) * 512);
      gload_lds16(gB + (size_t)i * 8 * K + k0, Bs + (w * 4 + i) * 512);
    }
    __syncthreads();
#pragma unroll
    for (int kk = 0; kk < 2; kk++) {
      bf16x8 af[4], bfr[4];
#pragma unroll
      for (int m = 0; m < 4; m++)
        af[m] = *(const bf16x8*)(As + (wr * 64 + m * 16 + l15) * 64 + kk * 32 + lg * 8);
#pragma unroll
      for (int n = 0; n < 4; n++)
        bfr[n] = *(const bf16x8*)(Bs + (wc * 64 + n * 16 + l15) * 64 + kk * 32 + lg * 8);
#pragma unroll
      for (int m = 0; m < 4; m++)
#pragma unroll
        for (int n = 0; n < 4; n++)
          acc[m][n] = __builtin_amdgcn_mfma_f32_16x16x32_bf16(af[m], bfr[n], acc[m][n], 0, 0, 0);
    }
  }
  const int r0 = m0 + wr * 64 + lg * 4;
  const int c0 = n0 + wc * 64 + l15;
#pragma unroll
  for (int m = 0; m < 4; m++)
#pragma unroll
    for (int n = 0; n < 4; n++)
#pragma unroll
      for (int i = 0; i < 4; i++) {
        size_t idx = (size_t)(r0 + m * 16 + i) * N + (c0 + n * 16);
        if (F32OUT) ((float*)C)[idx] = acc[m][n][i];
        else        ((bf16*)C)[idx]  = (bf16)acc[m][n][i];
      }
}

// ---------------- in-place RoPE on QKV cols [0,2560) ----------------
__global__ void k_rope(bf16* __restrict__ QKV) {
  const float L2B = 0.20762050593046007f;  // log2(10000)/64
  int tid = blockIdx.x * 256 + threadIdx.x;
  int row = tid / 320;
  int c8 = (tid - row * 320) * 8;
  int t = row & (T_SEQ - 1);
  bf16* p = QKV + (size_t)row * NQKV + c8;
  bf16x8 v = *(const bf16x8*)p;
  int ib = (c8 & 127) >> 1;
  bf16x8 o;
#pragma unroll
  for (int m = 0; m < 4; m++) {
    float inv = exp2f(-(float)(ib + m) * L2B);
    float ang = (float)t * inv;
    float cs, sn;
    __sincosf(ang, &sn, &cs);
    float x1 = (float)v[2 * m], x2 = (float)v[2 * m + 1];
    o[2 * m]     = (bf16)(x1 * cs - x2 * sn);
    o[2 * m + 1] = (bf16)(x1 * sn + x2 * cs);
  }
  *(bf16x8*)p = o;
}

// ---------------- flash attention (causal, GQA) ----------------
// 1 q-tile/block, 3 blocks/CU (41KB LDS); reg-staged K+V prefetch hidden under
// compute; wave-uniform running max (6 shuffles/tile); exp2 softmax; MFMA rowsum;
// defer-max THR=8 (wave-uniform branch).
#define LOADKV(kt) do {                                                                   \
    UNROLL for (int i = 0; i < 4; i++) {                                                  \
      int row_ = w * 16 + i * 4 + lg;                                                     \
      int col_ = (l15 ^ (row_ & 7)) * 8;                                                  \
      krg[i] = *(const uint4*)(Kbase + (size_t)((kt) * 64 + row_) * NQKV + col_);         \
      int d_ = (w * 4 + i) * 8 + (lane >> 3);                                             \
      int u_ = lane & 7;                                                                  \
      vrg[i] = *(const uint4*)(Vbase + (size_t)d_ * T_SEQ + (kt) * 64 + ((u_ ^ (d_ & 7)) * 8)); \
    }                                                                                     \
  } while (0)

#define WRITEKV() do {                                                                    \
    UNROLL for (int i = 0; i < 4; i++) {                                                  \
      *(uint4*)((char*)Ks + (w * 4 + i) * 1024 + lane * 16) = krg[i];                     \
      *(uint4*)((char*)Vs + (w * 4 + i) * 1024 + lane * 16) = vrg[i];                     \
    }                                                                                     \
  } while (0)

#define COMPUTE(kt) do {                                                                  \
    f32x4 s_[4] = {};                                                                     \
    const char* ks_ = (const char*)Ks;                                                    \
    __builtin_amdgcn_s_setprio(1);                                                        \
    UNROLL for (int kk = 0; kk < 4; kk++)                                                 \
      UNROLL for (int n = 0; n < 4; n++) {                                                \
        int row_ = n * 16 + l15;                                                          \
        int cb_ = (kk * 64 + lg * 16) ^ ((row_ & 7) << 4);                                \
        bf16x8 kf_ = *(const bf16x8*)(ks_ + row_ * 256 + cb_);                            \
        s_[n] = __builtin_amdgcn_mfma_f32_16x16x32_bf16(qreg[kk], kf_, s_[n], 0, 0, 0);   \
      }                                                                                   \
    __builtin_amdgcn_s_setprio(0);                                                        \
    if ((kt) == qt) {                                                                     \
      UNROLL for (int n = 0; n < 4; n++)                                                  \
        UNROLL for (int i = 0; i < 4; i++)                                                \
          if ((kt) * 64 + n * 16 + l15 > qt * 64 + w * 16 + lg * 4 + i)                   \
            s_[n][i] = -1e30f;                                                            \
    }                                                                                     \
    float vm_ = s_[0][0];                                                                 \
    UNROLL for (int n = 0; n < 4; n++)                                                    \
      UNROLL for (int i = 0; i < 4; i++) vm_ = fmaxf(vm_, s_[n][i]);                      \
    vm_ = fmaxf(vm_, __shfl_xor(vm_, 1));                                                 \
    vm_ = fmaxf(vm_, __shfl_xor(vm_, 2));                                                 \
    vm_ = fmaxf(vm_, __shfl_xor(vm_, 4));                                                 \
    vm_ = fmaxf(vm_, __shfl_xor(vm_, 8));                                                 \
    vm_ = fmaxf(vm_, __shfl_xor(vm_, 16));                                                \
    vm_ = fmaxf(vm_, __shfl_xor(vm_, 32));                                                \
    if (!(vm_ <= mw + 8.0f)) {                                                            \
      float mn_ = fmaxf(mw, vm_);                                                         \
      float al_ = __builtin_amdgcn_exp2f(mw - mn_);                                       \
      mw = mn_;                                                                           \
      UNROLL for (int i = 0; i < 4; i++) lrow[i] *= al_;                                  \
      UNROLL for (int n = 0; n < 8; n++)                                                  \
        UNROLL for (int i = 0; i < 4; i++) o[n][i] *= al_;                                \
    }                                                                                     \
    UNROLL for (int n = 0; n < 4; n++)                                                    \
      UNROLL for (int i = 0; i < 4; i++)                                                  \
        Ps[w][lg * 4 + i][n * 16 + l15] =                                                 \
            (bf16)__builtin_amdgcn_exp2f(s_[n][i] - mw);                                  \
    f32x4 rs_ = {};                                                                       \
    const char* vs_ = (const char*)Vs;                                                    \
    __builtin_amdgcn_s_setprio(1);                                                        \
    UNROLL for (int kc = 0; kc < 2; kc++) {                                               \
      bf16x8 pa_ = *(const bf16x8*)(&Ps[w][l15][kc * 32 + lg * 8]);                       \
      rs_ = __builtin_amdgcn_mfma_f32_16x16x32_bf16(pa_, ones_, rs_, 0, 0, 0);            \
      UNROLL for (int n = 0; n < 8; n++) {                                                \
        int d_ = n * 16 + l15;                                                            \
        bf16x8 vf_ = *(const bf16x8*)(vs_ + d_ * 128 + ((((kc << 2) + lg) ^ (d_ & 7)) << 4)); \
        o[n] = __builtin_amdgcn_mfma_f32_16x16x32_bf16(pa_, vf_, o[n], 0, 0, 0);          \
      }                                                                                   \
    }                                                                                     \
    __builtin_amdgcn_s_setprio(0);                                                        \
    UNROLL for (int i = 0; i < 4; i++) lrow[i] += rs_[i];                                 \
  } while (0)

__global__ __launch_bounds__(256, 3) void k_flash(const bf16* __restrict__ QKV,
                                                  const bf16* __restrict__ Vtg,
                                                  bf16* __restrict__ AO) {
  __shared__ __align__(16) bf16 Ks[64 * 128];   // [kv row]*256B, chunk XOR (row&7)
  __shared__ __align__(16) bf16 Vs[128 * 64];   // [d row]*128B,  chunk XOR (d&7)
  __shared__ __align__(16) bf16 Ps[4][16][68];  // stride 136B: conflict-free wr/rd
  const int qt = 31 - blockIdx.x;               // longest-first dispatch
  const int bh = blockIdx.y;
  const int b = bh >> 4, h = bh & 15, kvh = h >> 2;
  const int tid = threadIdx.x, lane = tid & 63, w = tid >> 6;
  const int l15 = lane & 15, lg = lane >> 4;
  const float qs = 0.12753102f;          // (1/sqrt(128)) * log2(e)

  bf16x8 qreg[4];
  {
    const size_t qo = (size_t)(b * T_SEQ + qt * 64 + w * 16 + l15) * NQKV + h * DHEAD;
    UNROLL for (int kk = 0; kk < 4; kk++) {
      bf16x8 a = *(const bf16x8*)(QKV + qo + kk * 32 + lg * 8);
      UNROLL for (int j = 0; j < 8; j++) a[j] = (bf16)((float)a[j] * qs);
      qreg[kk] = a;
    }
  }
  bf16x8 ones_;
  UNROLL for (int j = 0; j < 8; j++) ones_[j] = (bf16)1.0f;

  f32x4 o[8] = {};
  float lrow[4] = {0.f, 0.f, 0.f, 0.f};
  float mw = -1e30f;

  const bf16* Kbase = QKV + (size_t)b * T_SEQ * NQKV + DMODEL + kvh * DHEAD;
  const bf16* Vbase = Vtg + (size_t)(b * 4 + kvh) * 128 * T_SEQ;

  uint4 krg[4], vrg[4];
  LOADKV(0);
  WRITEKV();
  __syncthreads();

  const int NT = qt + 1;
  for (int kt = 0; kt < NT; kt++) {
    const bool pf = (kt + 1 < NT);
    if (pf) LOADKV(kt + 1);       // global->reg, in flight during compute
    COMPUTE(kt);
    if (pf) {
      __syncthreads();            // all reads of Ks/Vs done; loads landed under compute
      WRITEKV();
      __syncthreads();            // ds_writes visible (lgkm-only drain, cheap)
    }
  }

  const size_t obase = (size_t)(b * T_SEQ + qt * 64 + w * 16 + lg * 4) * DMODEL + h * DHEAD + l15;
  UNROLL for (int i = 0; i < 4; i++) {
    float inv = 1.0f / lrow[i];
    UNROLL for (int n = 0; n < 8; n++)
      AO[obase + (size_t)i * DMODEL + n * 16] = (bf16)(o[n][i] * inv);
  }
}

extern "C" void kernel_launch(void* const* d_in, const int* in_sizes, int n_in,
                              void* d_out, int out_size, void* d_ws, size_t ws_size,
                              hipStream_t stream) {
  const float* x  = (const float*)d_in[0];
  const float* Wq = (const float*)d_in[1];
  const float* Wk = (const float*)d_in[2];
  const float* Wv = (const float*)d_in[3];
  const float* Wo = (const float*)d_in[4];
  char* ws = (char*)d_ws;
  bf16* xb  = (bf16*)ws;                                             // 4096x2048
  bf16* WT  = (bf16*)(ws + 16777216ull);                             // 3072x2048 (WqT|WkT|WvT)
  bf16* WoT = (bf16*)(ws + 16777216ull + 12582912ull);               // 2048x2048
  bf16* QKV = (bf16*)(ws + 16777216ull + 12582912ull + 8388608ull);  // 4096x3072
  bf16* AO  = (bf16*)(ws + 16777216ull + 12582912ull + 8388608ull + 25165824ull); // 4096x2048
  bf16* Vtg = WT;   // WT is dead after the QKV GEMM; reuse first 4 MB for V^T
  float* out = (float*)d_out;

  k_cvt<<<8192, 256, 0, stream>>>(x, xb);
  k_twt<<<dim3(32, 32), 256, 0, stream>>>(Wq, WT, 2048, 2048);
  k_twt<<<dim3(32, 8), 256, 0, stream>>>(Wk, WT + (size_t)2048 * 2048, 2048, 512);
  k_twt<<<dim3(32, 8), 256, 0, stream>>>(Wv, WT + (size_t)2560 * 2048, 2048, 512);
  k_twt<<<dim3(32, 32), 256, 0, stream>>>(Wo, WoT, 2048, 2048);
  k_gemm<false><<<dim3(32, 24), 256, 0, stream>>>(xb, WT, QKV, 4096, 3072, 2048);
  k_rope<<<5120, 256, 0, stream>>>(QKV);
  k_vt<<<dim3(32, 2, 8), 256, 0, stream>>>(QKV, Vtg);
  k_flash<<<dim3(32, 32), 256, 0, stream>>>(QKV, Vtg, AO);
  k_gemm<true><<<dim3(32, 16), 256, 0, stream>>>(AO, WoT, out, 4096, 2048, 2048);
}

// Round 7
// 306.412 us; speedup vs baseline: 1.5559x; 1.5559x over previous
//
#include <hip/hip_runtime.h>
#include <stdint.h>

typedef __bf16 bf16;
typedef __bf16 bf16x8 __attribute__((ext_vector_type(8)));
typedef __bf16 bf16x4 __attribute__((ext_vector_type(4)));
typedef float  f32x4  __attribute__((ext_vector_type(4)));

#define T_SEQ  2048
#define NHEAD  16
#define DHEAD  128
#define DMODEL 2048
#define NQKV   3072   // 2048 Q | 512 K | 512 V per row
#define UNROLL _Pragma("unroll")

__device__ __forceinline__ void gload_lds16(const void* g, void* l) {
  __builtin_amdgcn_global_load_lds(
      (const __attribute__((address_space(1))) uint32_t*)g,
      (__attribute__((address_space(3))) uint32_t*)l, 16, 0, 0);
}

// ---------------- fused prep: x cast + 4 weight transposes ----------------
__device__ __forceinline__ void twt_body(const float* __restrict__ W,
                                         bf16* __restrict__ WT, int K, int N,
                                         int bx, int by, float (*t)[65]) {
  int k0 = bx * 64, n0 = by * 64;
  int r4 = threadIdx.x >> 6, c = threadIdx.x & 63;
#pragma unroll
  for (int i = 0; i < 16; i++) {
    int r = i * 4 + r4;
    t[r][c] = W[(size_t)(k0 + r) * N + n0 + c];
  }
  __syncthreads();
#pragma unroll
  for (int i = 0; i < 16; i++) {
    int r = i * 4 + r4;
    WT[(size_t)(n0 + r) * K + k0 + c] = (bf16)t[c][r];
  }
}

__global__ __launch_bounds__(256) void k_prep(const float* __restrict__ x,
                                              const float* __restrict__ Wq,
                                              const float* __restrict__ Wk,
                                              const float* __restrict__ Wv,
                                              const float* __restrict__ Wo,
                                              bf16* __restrict__ xb,
                                              bf16* __restrict__ WT,
                                              bf16* __restrict__ WoT) {
  __shared__ float t[64][65];
  const int blk = blockIdx.x;
  if (blk < 8192) {
    int i = (blk * 256 + threadIdx.x) * 4;
    float4 v = *(const float4*)(x + i);
    bf16x4 o = { (bf16)v.x, (bf16)v.y, (bf16)v.z, (bf16)v.w };
    *(bf16x4*)(xb + i) = o;
  } else if (blk < 9216) {
    int b = blk - 8192;
    twt_body(Wq, WT, 2048, 2048, b & 31, b >> 5, t);
  } else if (blk < 9472) {
    int b = blk - 9216;
    twt_body(Wk, WT + (size_t)2048 * 2048, 2048, 512, b & 31, b >> 5, t);
  } else if (blk < 9728) {
    int b = blk - 9472;
    twt_body(Wv, WT + (size_t)2560 * 2048, 2048, 512, b & 31, b >> 5, t);
  } else {
    int b = blk - 9728;
    twt_body(Wo, WoT, 2048, 2048, b & 31, b >> 5, t);
  }
}

// ---------------- fused post: RoPE (Q,K cols) + V transpose ----------------
__global__ __launch_bounds__(256) void k_post(bf16* __restrict__ QKV,
                                              bf16* __restrict__ Vtg) {
  __shared__ bf16 t[64][65];
  const int blk = blockIdx.x;
  if (blk < 5120) {
    const float L2B = 0.20762050593046007f;  // log2(10000)/64
    int tid = blk * 256 + threadIdx.x;
    int row = tid / 320;
    int c8 = (tid - row * 320) * 8;
    int tt = row & (T_SEQ - 1);
    bf16* p = QKV + (size_t)row * NQKV + c8;
    bf16x8 v = *(const bf16x8*)p;
    int ib = (c8 & 127) >> 1;
    bf16x8 o;
#pragma unroll
    for (int m = 0; m < 4; m++) {
      float inv = exp2f(-(float)(ib + m) * L2B);
      float ang = (float)tt * inv;
      float cs, sn;
      __sincosf(ang, &sn, &cs);
      float x1 = (float)v[2 * m], x2 = (float)v[2 * m + 1];
      o[2 * m]     = (bf16)(x1 * cs - x2 * sn);
      o[2 * m + 1] = (bf16)(x1 * sn + x2 * cs);
    }
    *(bf16x8*)p = o;
  } else {
    int bb = blk - 5120;                 // 512 blocks: 32 x 2 x 8
    int bx = bb & 31, by = (bb >> 5) & 1, g = bb >> 6;
    const int t0 = bx * 64, d0 = by * 64;
    const int b = g >> 2, kvh = g & 3;
    const bf16* src = QKV + (size_t)b * T_SEQ * NQKV + 2560 + kvh * DHEAD;
    bf16* dst = Vtg + ((size_t)(b * 4 + kvh) * 128 + d0) * T_SEQ + t0;
    const int r4 = threadIdx.x >> 6, c = threadIdx.x & 63;
#pragma unroll
    for (int i = 0; i < 16; i++) {
      int r = i * 4 + r4;
      t[r][c] = src[(size_t)(t0 + r) * NQKV + d0 + c];
    }
    __syncthreads();
#pragma unroll
    for (int i = 0; i < 16; i++) {
      int r = i * 4 + r4;
      dst[(size_t)r * T_SEQ + c] = t[c][r];
    }
  }
}

// ---------------- GEMM: C[M,N] = A[M,K] * BT[N,K]^T  (m97 + XCD swizzle) --------
template<bool F32OUT>
__global__ __launch_bounds__(256) void k_gemm(const bf16* __restrict__ A,
                                              const bf16* __restrict__ BT,
                                              void* __restrict__ C,
                                              int M, int N, int K) {
  __shared__ __align__(16) bf16 As[128 * 64];
  __shared__ __align__(16) bf16 Bs[128 * 64];
  const int nwg = gridDim.x * gridDim.y;
  const int orig = blockIdx.y * gridDim.x + blockIdx.x;
  const int tile = (orig & 7) * (nwg >> 3) + (orig >> 3);   // nwg % 8 == 0
  const int m0 = (tile % gridDim.x) * 128, n0 = (tile / gridDim.x) * 128;
  const int tid = threadIdx.x;
  const int lane = tid & 63, w = tid >> 6;
  const int wr = w >> 1, wc = w & 1;
  const int l15 = lane & 15, lg = lane >> 4;
  f32x4 acc[4][4] = {};

  const int rA = w * 32 + (lane >> 3);
  const int cA = (lane & 7) * 8;
  const bf16* gA = A  + (size_t)(m0 + rA) * K + cA;
  const bf16* gB = BT + (size_t)(n0 + rA) * K + cA;

  for (int k0 = 0; k0 < K; k0 += 64) {
    __syncthreads();
#pragma unroll
    for (int i = 0; i < 4; i++) {
      gload_lds16(gA + (size_t)i * 8 * K + k0, As + (w * 4 + i) * 512);
      gload_lds16(gB + (size_t)i * 8 * K + k0, Bs + (w * 4 + i) * 512);
    }
    __syncthreads();
#pragma unroll
    for (int kk = 0; kk < 2; kk++) {
      bf16x8 af[4], bfr[4];
#pragma unroll
      for (int m = 0; m < 4; m++)
        af[m] = *(const bf16x8*)(As + (wr * 64 + m * 16 + l15) * 64 + kk * 32 + lg * 8);
#pragma unroll
      for (int n = 0; n < 4; n++)
        bfr[n] = *(const bf16x8*)(Bs + (wc * 64 + n * 16 + l15) * 64 + kk * 32 + lg * 8);
#pragma unroll
      for (int m = 0; m < 4; m++)
#pragma unroll
        for (int n = 0; n < 4; n++)
          acc[m][n] = __builtin_amdgcn_mfma_f32_16x16x32_bf16(af[m], bfr[n], acc[m][n], 0, 0, 0);
    }
  }
  const int r0 = m0 + wr * 64 + lg * 4;
  const int c0 = n0 + wc * 64 + l15;
#pragma unroll
  for (int m = 0; m < 4; m++)
#pragma unroll
    for (int n = 0; n < 4; n++)
#pragma unroll
      for (int i = 0; i < 4; i++) {
        size_t idx = (size_t)(r0 + m * 16 + i) * N + (c0 + n * 16);
        if (F32OUT) ((float*)C)[idx] = acc[m][n][i];
        else        ((bf16*)C)[idx]  = (bf16)acc[m][n][i];
      }
}

// ---------------- flash attention (causal, GQA), head-paired ----------------
// Round-4 proven structure: dbuf gload_lds K/V prefetch issued before compute,
// exp2 softmax, MFMA row-sum, defer-max THR=8. One q-tile, TWO heads (same kvh)
// per block: 2.0 computes/stage (was 1.52), half the total stages.
#define COMPUTE(qreg, o, mrow, lrow, qt_this, kt, cur) do {                               \
    f32x4 s_[4] = {};                                                                     \
    const char* ks_ = (const char*)Ks[cur];                                               \
    UNROLL for (int kk = 0; kk < 4; kk++)                                                 \
      UNROLL for (int n = 0; n < 4; n++) {                                                \
        int row_ = n * 16 + l15;                                                          \
        int cb_ = (kk * 64 + lg * 16) ^ ((row_ & 7) << 4);                                \
        bf16x8 kf_ = *(const bf16x8*)(ks_ + row_ * 256 + cb_);                            \
        s_[n] = __builtin_amdgcn_mfma_f32_16x16x32_bf16(qreg[kk], kf_, s_[n], 0, 0, 0);   \
      }                                                                                   \
    if ((kt) == (qt_this)) {                                                              \
      UNROLL for (int n = 0; n < 4; n++)                                                  \
        UNROLL for (int i = 0; i < 4; i++)                                                \
          if ((kt) * 64 + n * 16 + l15 > (qt_this) * 64 + w * 16 + lg * 4 + i)            \
            s_[n][i] = -1e30f;                                                            \
    }                                                                                     \
    float pm_[4];                                                                         \
    UNROLL for (int i = 0; i < 4; i++)                                                    \
      pm_[i] = fmaxf(fmaxf(s_[0][i], s_[1][i]), fmaxf(s_[2][i], s_[3][i]));               \
    UNROLL for (int i = 0; i < 4; i++) {                                                  \
      float v_ = pm_[i];                                                                  \
      v_ = fmaxf(v_, __shfl_xor(v_, 1));                                                  \
      v_ = fmaxf(v_, __shfl_xor(v_, 2));                                                  \
      v_ = fmaxf(v_, __shfl_xor(v_, 4));                                                  \
      v_ = fmaxf(v_, __shfl_xor(v_, 8));                                                  \
      pm_[i] = v_;                                                                        \
    }                                                                                     \
    bool ok_ = true;                                                                      \
    UNROLL for (int i = 0; i < 4; i++) ok_ = ok_ && (pm_[i] <= mrow[i] + 8.0f);           \
    if (!__all(ok_)) {                                                                    \
      UNROLL for (int i = 0; i < 4; i++) {                                                \
        float mn_ = fmaxf(mrow[i], pm_[i]);                                               \
        float al_ = __builtin_amdgcn_exp2f(mrow[i] - mn_);                                \
        mrow[i] = mn_;                                                                    \
        lrow[i] *= al_;                                                                   \
        UNROLL for (int n = 0; n < 8; n++) o[n][i] *= al_;                                \
      }                                                                                   \
    }                                                                                     \
    UNROLL for (int n = 0; n < 4; n++)                                                    \
      UNROLL for (int i = 0; i < 4; i++)                                                  \
        Ps[w][lg * 4 + i][n * 16 + l15] =                                                 \
            (bf16)__builtin_amdgcn_exp2f(s_[n][i] - mrow[i]);                             \
    f32x4 rs_ = {};                                                                       \
    const char* vs_ = (const char*)Vs[cur];                                               \
    UNROLL for (int kc = 0; kc < 2; kc++) {                                               \
      bf16x8 pa_ = *(const bf16x8*)(&Ps[w][l15][kc * 32 + lg * 8]);                       \
      rs_ = __builtin_amdgcn_mfma_f32_16x16x32_bf16(pa_, ones_, rs_, 0, 0, 0);            \
      UNROLL for (int n = 0; n < 8; n++) {                                                \
        int d_ = n * 16 + l15;                                                            \
        bf16x8 vf_ = *(const bf16x8*)(vs_ + d_ * 128 + ((((kc << 2) + lg) ^ (d_ & 7)) << 4)); \
        o[n] = __builtin_amdgcn_mfma_f32_16x16x32_bf16(pa_, vf_, o[n], 0, 0, 0);          \
      }                                                                                   \
    }                                                                                     \
    UNROLL for (int i = 0; i < 4; i++) lrow[i] += rs_[i];                                 \
  } while (0)

__global__ __launch_bounds__(256) void k_flash(const bf16* __restrict__ QKV,
                                               const bf16* __restrict__ Vtg,
                                               bf16* __restrict__ AO) {
  __shared__ __align__(16) bf16 Ks[2][64 * 128];   // [kv row]*256B, chunk XOR (row&7)
  __shared__ __align__(16) bf16 Vs[2][128 * 64];   // [d row]*128B,  chunk XOR (d&7)
  __shared__ __align__(16) bf16 Ps[4][16][72];
  // 512 blocks; XCD swizzle: XCD c serves one (b,kvh) pair (K+V = 1MB in L2),
  // qt descending within each chunk (longest-first dispatch).
  const int orig = blockIdx.y * 32 + blockIdx.x;
  const int fin  = ((orig & 7) << 6) | (orig >> 3);
  const int bhp  = fin >> 5;                 // b*8 + kvh*2 + hp
  const int qt   = 31 - (fin & 31);
  const int b = bhp >> 3, kvh = (bhp >> 1) & 3, hp = bhp & 1;
  const int h0 = kvh * 4 + hp * 2, h1 = h0 + 1;
  const int tid = threadIdx.x, lane = tid & 63, w = tid >> 6;
  const int l15 = lane & 15, lg = lane >> 4;
  const float qs = 0.12753102f;              // (1/sqrt(128)) * log2(e)

  bf16x8 qA[4], qB[4];
  {
    const size_t qoA = (size_t)(b * T_SEQ + qt * 64 + w * 16 + l15) * NQKV + h0 * DHEAD;
    const size_t qoB = (size_t)(b * T_SEQ + qt * 64 + w * 16 + l15) * NQKV + h1 * DHEAD;
    UNROLL for (int kk = 0; kk < 4; kk++) {
      bf16x8 a = *(const bf16x8*)(QKV + qoA + kk * 32 + lg * 8);
      bf16x8 bb = *(const bf16x8*)(QKV + qoB + kk * 32 + lg * 8);
      UNROLL for (int j = 0; j < 8; j++) {
        a[j] = (bf16)((float)a[j] * qs);
        bb[j] = (bf16)((float)bb[j] * qs);
      }
      qA[kk] = a; qB[kk] = bb;
    }
  }
  bf16x8 ones_;
  UNROLL for (int j = 0; j < 8; j++) ones_[j] = (bf16)1.0f;

  f32x4 oA[8] = {}, oB[8] = {};
  float mA[4], lAc[4], mB[4], lBc[4];
  UNROLL for (int i = 0; i < 4; i++) { mA[i] = mB[i] = -1e30f; lAc[i] = lBc[i] = 0.f; }

  const bf16* Kbase = QKV + (size_t)b * T_SEQ * NQKV + DMODEL + kvh * DHEAD;
  const bf16* Vbase = Vtg + (size_t)(b * 4 + kvh) * 128 * T_SEQ;

  auto issueK = [&](int buf, int kt) {
    UNROLL for (int i = 0; i < 4; i++) {
      int row = w * 16 + i * 4 + lg;
      int col = (l15 ^ (row & 7)) * 8;
      gload_lds16(Kbase + (size_t)(kt * 64 + row) * NQKV + col,
                  Ks[buf] + (w * 4 + i) * 512);
    }
  };
  auto issueV = [&](int buf, int kt) {
    UNROLL for (int i = 0; i < 4; i++) {
      int d = (w * 4 + i) * 8 + (lane >> 3);
      int u = lane & 7;
      gload_lds16(Vbase + (size_t)d * T_SEQ + kt * 64 + ((u ^ (d & 7)) * 8),
                  Vs[buf] + (w * 4 + i) * 512);
    }
  };

  issueK(0, 0);
  issueV(0, 0);
  __syncthreads();

  const int NT = qt + 1;
  for (int kt = 0; kt < NT; kt++) {
    const int cur = kt & 1, nxt = cur ^ 1;
    if (kt + 1 < NT) { issueK(nxt, kt + 1); issueV(nxt, kt + 1); }
    COMPUTE(qA, oA, mA, lAc, qt, kt, cur);
    COMPUTE(qB, oB, mB, lBc, qt, kt, cur);
    __syncthreads();
  }

  {
    const size_t obase = (size_t)(b * T_SEQ + qt * 64 + w * 16 + lg * 4) * DMODEL + h0 * DHEAD + l15;
    UNROLL for (int i = 0; i < 4; i++) {
      float inv = 1.0f / lAc[i];
      UNROLL for (int n = 0; n < 8; n++)
        AO[obase + (size_t)i * DMODEL + n * 16] = (bf16)(oA[n][i] * inv);
    }
  }
  {
    const size_t obase = (size_t)(b * T_SEQ + qt * 64 + w * 16 + lg * 4) * DMODEL + h1 * DHEAD + l15;
    UNROLL for (int i = 0; i < 4; i++) {
      float inv = 1.0f / lBc[i];
      UNROLL for (int n = 0; n < 8; n++)
        AO[obase + (size_t)i * DMODEL + n * 16] = (bf16)(oB[n][i] * inv);
    }
  }
}

extern "C" void kernel_launch(void* const* d_in, const int* in_sizes, int n_in,
                              void* d_out, int out_size, void* d_ws, size_t ws_size,
                              hipStream_t stream) {
  const float* x  = (const float*)d_in[0];
  const float* Wq = (const float*)d_in[1];
  const float* Wk = (const float*)d_in[2];
  const float* Wv = (const float*)d_in[3];
  const float* Wo = (const float*)d_in[4];
  char* ws = (char*)d_ws;
  bf16* xb  = (bf16*)ws;                                             // 4096x2048
  bf16* WT  = (bf16*)(ws + 16777216ull);                             // 3072x2048 (WqT|WkT|WvT)
  bf16* WoT = (bf16*)(ws + 16777216ull + 12582912ull);               // 2048x2048
  bf16* QKV = (bf16*)(ws + 16777216ull + 12582912ull + 8388608ull);  // 4096x3072
  bf16* AO  = (bf16*)(ws + 16777216ull + 12582912ull + 8388608ull + 25165824ull); // 4096x2048
  bf16* Vtg = WT;   // WT is dead after the QKV GEMM; reuse first 4 MB for V^T
  float* out = (float*)d_out;

  k_prep<<<10752, 256, 0, stream>>>(x, Wq, Wk, Wv, Wo, xb, WT, WoT);
  k_gemm<false><<<dim3(32, 24), 256, 0, stream>>>(xb, WT, QKV, 4096, 3072, 2048);
  k_post<<<5632, 256, 0, stream>>>(QKV, Vtg);
  k_flash<<<dim3(32, 16), 256, 0, stream>>>(QKV, Vtg, AO);
  k_gemm<true><<<dim3(32, 16), 256, 0, stream>>>(AO, WoT, out, 4096, 2048, 2048);
}

// Round 8
// 266.367 us; speedup vs baseline: 1.7899x; 1.1503x over previous
//
#include <hip/hip_runtime.h>
#include <stdint.h>

typedef __bf16 bf16;
typedef __bf16 bf16x8 __attribute__((ext_vector_type(8)));
typedef __bf16 bf16x4 __attribute__((ext_vector_type(4)));
typedef float  f32x4  __attribute__((ext_vector_type(4)));

#define T_SEQ  2048
#define NHEAD  16
#define DHEAD  128
#define DMODEL 2048
#define NQKV   3072   // 2048 Q | 512 K | 512 V per row
#define UNROLL _Pragma("unroll")

__device__ __forceinline__ void gload_lds16(const void* g, void* l) {
  __builtin_amdgcn_global_load_lds(
      (const __attribute__((address_space(1))) uint32_t*)g,
      (__attribute__((address_space(3))) uint32_t*)l, 16, 0, 0);
}

// ---------------- fused prep: x cast + 4 weight transposes ----------------
__device__ __forceinline__ void twt_body(const float* __restrict__ W,
                                         bf16* __restrict__ WT, int K, int N,
                                         int bx, int by, float (*t)[65]) {
  int k0 = bx * 64, n0 = by * 64;
  int r4 = threadIdx.x >> 6, c = threadIdx.x & 63;
#pragma unroll
  for (int i = 0; i < 16; i++) {
    int r = i * 4 + r4;
    t[r][c] = W[(size_t)(k0 + r) * N + n0 + c];
  }
  __syncthreads();
#pragma unroll
  for (int i = 0; i < 16; i++) {
    int r = i * 4 + r4;
    WT[(size_t)(n0 + r) * K + k0 + c] = (bf16)t[c][r];
  }
}

__global__ __launch_bounds__(256) void k_prep(const float* __restrict__ x,
                                              const float* __restrict__ Wq,
                                              const float* __restrict__ Wk,
                                              const float* __restrict__ Wv,
                                              const float* __restrict__ Wo,
                                              bf16* __restrict__ xb,
                                              bf16* __restrict__ WT,
                                              bf16* __restrict__ WoT) {
  __shared__ float t[64][65];
  const int blk = blockIdx.x;
  if (blk < 8192) {
    int i = (blk * 256 + threadIdx.x) * 4;
    float4 v = *(const float4*)(x + i);
    bf16x4 o = { (bf16)v.x, (bf16)v.y, (bf16)v.z, (bf16)v.w };
    *(bf16x4*)(xb + i) = o;
  } else if (blk < 9216) {
    int b = blk - 8192;
    twt_body(Wq, WT, 2048, 2048, b & 31, b >> 5, t);
  } else if (blk < 9472) {
    int b = blk - 9216;
    twt_body(Wk, WT + (size_t)2048 * 2048, 2048, 512, b & 31, b >> 5, t);
  } else if (blk < 9728) {
    int b = blk - 9472;
    twt_body(Wv, WT + (size_t)2560 * 2048, 2048, 512, b & 31, b >> 5, t);
  } else {
    int b = blk - 9728;
    twt_body(Wo, WoT, 2048, 2048, b & 31, b >> 5, t);
  }
}

// ---------------- fused post: RoPE (Q,K cols) + V transpose ----------------
__global__ __launch_bounds__(256) void k_post(bf16* __restrict__ QKV,
                                              bf16* __restrict__ Vtg) {
  __shared__ bf16 t[64][65];
  const int blk = blockIdx.x;
  if (blk < 5120) {
    const float L2B = 0.20762050593046007f;  // log2(10000)/64
    int tid = blk * 256 + threadIdx.x;
    int row = tid / 320;
    int c8 = (tid - row * 320) * 8;
    int tt = row & (T_SEQ - 1);
    bf16* p = QKV + (size_t)row * NQKV + c8;
    bf16x8 v = *(const bf16x8*)p;
    int ib = (c8 & 127) >> 1;
    bf16x8 o;
#pragma unroll
    for (int m = 0; m < 4; m++) {
      float inv = exp2f(-(float)(ib + m) * L2B);
      float ang = (float)tt * inv;
      float cs, sn;
      __sincosf(ang, &sn, &cs);
      float x1 = (float)v[2 * m], x2 = (float)v[2 * m + 1];
      o[2 * m]     = (bf16)(x1 * cs - x2 * sn);
      o[2 * m + 1] = (bf16)(x1 * sn + x2 * cs);
    }
    *(bf16x8*)p = o;
  } else {
    int bb = blk - 5120;                 // 512 blocks: 32 x 2 x 8
    int bx = bb & 31, by = (bb >> 5) & 1, g = bb >> 6;
    const int t0 = bx * 64, d0 = by * 64;
    const int b = g >> 2, kvh = g & 3;
    const bf16* src = QKV + (size_t)b * T_SEQ * NQKV + 2560 + kvh * DHEAD;
    bf16* dst = Vtg + ((size_t)(b * 4 + kvh) * 128 + d0) * T_SEQ + t0;
    const int r4 = threadIdx.x >> 6, c = threadIdx.x & 63;
#pragma unroll
    for (int i = 0; i < 16; i++) {
      int r = i * 4 + r4;
      t[r][c] = src[(size_t)(t0 + r) * NQKV + d0 + c];
    }
    __syncthreads();
#pragma unroll
    for (int i = 0; i < 16; i++) {
      int r = i * 4 + r4;
      dst[(size_t)r * T_SEQ + c] = t[c][r];
    }
  }
}

// ---------------- GEMM: C[M,N] = A[M,K] * BT[N,K]^T  (m97 + XCD swizzle) --------
template<bool F32OUT>
__global__ __launch_bounds__(256) void k_gemm(const bf16* __restrict__ A,
                                              const bf16* __restrict__ BT,
                                              void* __restrict__ C,
                                              int M, int N, int K) {
  __shared__ __align__(16) bf16 As[128 * 64];
  __shared__ __align__(16) bf16 Bs[128 * 64];
  const int nwg = gridDim.x * gridDim.y;
  const int orig = blockIdx.y * gridDim.x + blockIdx.x;
  const int tile = (orig & 7) * (nwg >> 3) + (orig >> 3);   // nwg % 8 == 0
  const int m0 = (tile % gridDim.x) * 128, n0 = (tile / gridDim.x) * 128;
  const int tid = threadIdx.x;
  const int lane = tid & 63, w = tid >> 6;
  const int wr = w >> 1, wc = w & 1;
  const int l15 = lane & 15, lg = lane >> 4;
  f32x4 acc[4][4] = {};

  const int rA = w * 32 + (lane >> 3);
  const int cA = (lane & 7) * 8;
  const bf16* gA = A  + (size_t)(m0 + rA) * K + cA;
  const bf16* gB = BT + (size_t)(n0 + rA) * K + cA;

  for (int k0 = 0; k0 < K; k0 += 64) {
    __syncthreads();
#pragma unroll
    for (int i = 0; i < 4; i++) {
      gload_lds16(gA + (size_t)i * 8 * K + k0, As + (w * 4 + i) * 512);
      gload_lds16(gB + (size_t)i * 8 * K + k0, Bs + (w * 4 + i) * 512);
    }
    __syncthreads();
#pragma unroll
    for (int kk = 0; kk < 2; kk++) {
      bf16x8 af[4], bfr[4];
#pragma unroll
      for (int m = 0; m < 4; m++)
        af[m] = *(const bf16x8*)(As + (wr * 64 + m * 16 + l15) * 64 + kk * 32 + lg * 8);
#pragma unroll
      for (int n = 0; n < 4; n++)
        bfr[n] = *(const bf16x8*)(Bs + (wc * 64 + n * 16 + l15) * 64 + kk * 32 + lg * 8);
#pragma unroll
      for (int m = 0; m < 4; m++)
#pragma unroll
        for (int n = 0; n < 4; n++)
          acc[m][n] = __builtin_amdgcn_mfma_f32_16x16x32_bf16(af[m], bfr[n], acc[m][n], 0, 0, 0);
    }
  }
  const int r0 = m0 + wr * 64 + lg * 4;
  const int c0 = n0 + wc * 64 + l15;
#pragma unroll
  for (int m = 0; m < 4; m++)
#pragma unroll
    for (int n = 0; n < 4; n++)
#pragma unroll
      for (int i = 0; i < 4; i++) {
        size_t idx = (size_t)(r0 + m * 16 + i) * N + (c0 + n * 16);
        if (F32OUT) ((float*)C)[idx] = acc[m][n][i];
        else        ((bf16*)C)[idx]  = (bf16)acc[m][n][i];
      }
}

// ---------------- flash attention (causal, GQA), head-paired, shared-operand ----
// Swapped QK (lane holds S[kv][q=l15]); kf/vf reads shared by both heads;
// P packed to LDS via 4x ds_write_b64/head; per-q max (2 shfl) + defer-max;
// exp2 softmax; in-lane rowsum (2 shfl).
#define COMPUTE2(kt, cur) do {                                                            \
    f32x4 sA_[4] = {}, sB_[4] = {};                                                       \
    const char* ks_ = (const char*)Ks[cur];                                               \
    __builtin_amdgcn_s_setprio(1);                                                        \
    UNROLL for (int kk = 0; kk < 4; kk++)                                                 \
      UNROLL for (int n = 0; n < 4; n++) {                                                \
        int row_ = n * 16 + l15;                                                          \
        int cb_ = (kk * 64 + lg * 16) ^ ((row_ & 7) << 4);                                \
        bf16x8 kf_ = *(const bf16x8*)(ks_ + row_ * 256 + cb_);                            \
        sA_[n] = __builtin_amdgcn_mfma_f32_16x16x32_bf16(kf_, qA[kk], sA_[n], 0, 0, 0);   \
        sB_[n] = __builtin_amdgcn_mfma_f32_16x16x32_bf16(kf_, qB[kk], sB_[n], 0, 0, 0);   \
      }                                                                                   \
    __builtin_amdgcn_s_setprio(0);                                                        \
    float vmA_ = -1e30f, vmB_ = -1e30f;                                                   \
    if ((kt) == qt) {                                                                     \
      UNROLL for (int n = 0; n < 4; n++)                                                  \
        UNROLL for (int i = 0; i < 4; i++) {                                              \
          if ((kt) * 64 + n * 16 + lg * 4 + i > qglob) {                                  \
            sA_[n][i] = -1e30f; sB_[n][i] = -1e30f;                                       \
          }                                                                               \
          vmA_ = fmaxf(vmA_, sA_[n][i]);                                                  \
          vmB_ = fmaxf(vmB_, sB_[n][i]);                                                  \
        }                                                                                 \
    } else {                                                                              \
      UNROLL for (int n = 0; n < 4; n++)                                                  \
        UNROLL for (int i = 0; i < 4; i++) {                                              \
          vmA_ = fmaxf(vmA_, sA_[n][i]);                                                  \
          vmB_ = fmaxf(vmB_, sB_[n][i]);                                                  \
        }                                                                                 \
    }                                                                                     \
    vmA_ = fmaxf(vmA_, __shfl_xor(vmA_, 16));                                             \
    vmA_ = fmaxf(vmA_, __shfl_xor(vmA_, 32));                                             \
    vmB_ = fmaxf(vmB_, __shfl_xor(vmB_, 16));                                             \
    vmB_ = fmaxf(vmB_, __shfl_xor(vmB_, 32));                                             \
    if (!__all((vmA_ <= mA + 8.0f) && (vmB_ <= mB + 8.0f))) {                             \
      float mnA_ = fmaxf(mA, vmA_), mnB_ = fmaxf(mB, vmB_);                               \
      float alA_ = __builtin_amdgcn_exp2f(mA - mnA_);                                     \
      float alB_ = __builtin_amdgcn_exp2f(mB - mnB_);                                     \
      mA = mnA_; mB = mnB_;                                                               \
      lA *= alA_; lB *= alB_;                                                             \
      UNROLL for (int i = 0; i < 4; i++) {                                                \
        int src_ = (lane & 48) + ((lane >> 2) & 12) + i;                                  \
        float aA_ = __shfl(alA_, src_);                                                   \
        float aB_ = __shfl(alB_, src_);                                                   \
        UNROLL for (int n = 0; n < 8; n++) { oA[n][i] *= aA_; oB[n][i] *= aB_; }          \
      }                                                                                   \
    }                                                                                     \
    bf16x8 paA0_, paA1_, paB0_, paB1_;                                                    \
    {                                                                                     \
      float rs_ = 0.f;                                                                    \
      UNROLL for (int n = 0; n < 4; n++) {                                                \
        bf16x4 pk_;                                                                       \
        UNROLL for (int i = 0; i < 4; i++) {                                              \
          float pv_ = __builtin_amdgcn_exp2f(sA_[n][i] - mA);                             \
          rs_ += pv_;                                                                     \
          pk_[i] = (bf16)pv_;                                                             \
        }                                                                                 \
        *(bf16x4*)(&Ps[w][l15][n * 16 + lg * 4]) = pk_;                                   \
      }                                                                                   \
      rs_ += __shfl_xor(rs_, 16);                                                         \
      rs_ += __shfl_xor(rs_, 32);                                                         \
      lA += rs_;                                                                          \
      paA0_ = *(const bf16x8*)(&Ps[w][l15][lg * 8]);                                      \
      paA1_ = *(const bf16x8*)(&Ps[w][l15][32 + lg * 8]);                                 \
    }                                                                                     \
    {                                                                                     \
      float rs_ = 0.f;                                                                    \
      UNROLL for (int n = 0; n < 4; n++) {                                                \
        bf16x4 pk_;                                                                       \
        UNROLL for (int i = 0; i < 4; i++) {                                              \
          float pv_ = __builtin_amdgcn_exp2f(sB_[n][i] - mB);                             \
          rs_ += pv_;                                                                     \
          pk_[i] = (bf16)pv_;                                                             \
        }                                                                                 \
        *(bf16x4*)(&Ps[w][l15][n * 16 + lg * 4]) = pk_;                                   \
      }                                                                                   \
      rs_ += __shfl_xor(rs_, 16);                                                         \
      rs_ += __shfl_xor(rs_, 32);                                                         \
      lB += rs_;                                                                          \
      paB0_ = *(const bf16x8*)(&Ps[w][l15][lg * 8]);                                      \
      paB1_ = *(const bf16x8*)(&Ps[w][l15][32 + lg * 8]);                                 \
    }                                                                                     \
    const char* vs_ = (const char*)Vs[cur];                                               \
    __builtin_amdgcn_s_setprio(1);                                                        \
    UNROLL for (int n = 0; n < 8; n++) {                                                  \
      int d_ = n * 16 + l15;                                                              \
      bf16x8 vf0_ = *(const bf16x8*)(vs_ + d_ * 128 + (((lg) ^ (d_ & 7)) << 4));          \
      oA[n] = __builtin_amdgcn_mfma_f32_16x16x32_bf16(paA0_, vf0_, oA[n], 0, 0, 0);       \
      oB[n] = __builtin_amdgcn_mfma_f32_16x16x32_bf16(paB0_, vf0_, oB[n], 0, 0, 0);       \
      bf16x8 vf1_ = *(const bf16x8*)(vs_ + d_ * 128 + (((4 + lg) ^ (d_ & 7)) << 4));      \
      oA[n] = __builtin_amdgcn_mfma_f32_16x16x32_bf16(paA1_, vf1_, oA[n], 0, 0, 0);       \
      oB[n] = __builtin_amdgcn_mfma_f32_16x16x32_bf16(paB1_, vf1_, oB[n], 0, 0, 0);       \
    }                                                                                     \
    __builtin_amdgcn_s_setprio(0);                                                        \
  } while (0)

__global__ __launch_bounds__(256) void k_flash(const bf16* __restrict__ QKV,
                                               const bf16* __restrict__ Vtg,
                                               bf16* __restrict__ AO) {
  __shared__ __align__(16) bf16 Ks[2][64 * 128];   // [kv row]*256B, chunk XOR (row&7)
  __shared__ __align__(16) bf16 Vs[2][128 * 64];   // [d row]*128B,  chunk XOR (d&7)
  __shared__ __align__(16) bf16 Ps[4][16][72];     // [q][kv], 144B rows (16B-aligned)
  const int orig = blockIdx.y * 32 + blockIdx.x;
  const int fin  = ((orig & 7) << 6) | (orig >> 3);
  const int bhp  = fin >> 5;                 // b*8 + kvh*2 + hp
  const int qt   = 31 - (fin & 31);
  const int b = bhp >> 3, kvh = (bhp >> 1) & 3, hp = bhp & 1;
  const int h0 = kvh * 4 + hp * 2, h1 = h0 + 1;
  const int tid = threadIdx.x, lane = tid & 63, w = tid >> 6;
  const int l15 = lane & 15, lg = lane >> 4;
  const int qglob = qt * 64 + w * 16 + l15;
  const float qs = 0.12753102f;              // (1/sqrt(128)) * log2(e)

  bf16x8 qA[4], qB[4];
  {
    const size_t qoA = (size_t)(b * T_SEQ + qt * 64 + w * 16 + l15) * NQKV + h0 * DHEAD;
    const size_t qoB = (size_t)(b * T_SEQ + qt * 64 + w * 16 + l15) * NQKV + h1 * DHEAD;
    UNROLL for (int kk = 0; kk < 4; kk++) {
      bf16x8 a = *(const bf16x8*)(QKV + qoA + kk * 32 + lg * 8);
      bf16x8 bb = *(const bf16x8*)(QKV + qoB + kk * 32 + lg * 8);
      UNROLL for (int j = 0; j < 8; j++) {
        a[j] = (bf16)((float)a[j] * qs);
        bb[j] = (bf16)((float)bb[j] * qs);
      }
      qA[kk] = a; qB[kk] = bb;
    }
  }

  f32x4 oA[8] = {}, oB[8] = {};
  float mA = -1e30f, mB = -1e30f, lA = 0.f, lB = 0.f;

  const bf16* Kbase = QKV + (size_t)b * T_SEQ * NQKV + DMODEL + kvh * DHEAD;
  const bf16* Vbase = Vtg + (size_t)(b * 4 + kvh) * 128 * T_SEQ;

  auto issueK = [&](int buf, int kt) {
    UNROLL for (int i = 0; i < 4; i++) {
      int row = w * 16 + i * 4 + lg;
      int col = (l15 ^ (row & 7)) * 8;
      gload_lds16(Kbase + (size_t)(kt * 64 + row) * NQKV + col,
                  Ks[buf] + (w * 4 + i) * 512);
    }
  };
  auto issueV = [&](int buf, int kt) {
    UNROLL for (int i = 0; i < 4; i++) {
      int d = (w * 4 + i) * 8 + (lane >> 3);
      int u = lane & 7;
      gload_lds16(Vbase + (size_t)d * T_SEQ + kt * 64 + ((u ^ (d & 7)) * 8),
                  Vs[buf] + (w * 4 + i) * 512);
    }
  };

  issueK(0, 0);
  issueV(0, 0);
  __syncthreads();

  const int NT = qt + 1;
  for (int kt = 0; kt < NT; kt++) {
    const int cur = kt & 1, nxt = cur ^ 1;
    if (kt + 1 < NT) { issueK(nxt, kt + 1); issueV(nxt, kt + 1); }
    COMPUTE2(kt, cur);
    __syncthreads();
  }

  {
    const size_t ob0 = (size_t)(b * T_SEQ + qt * 64 + w * 16 + lg * 4) * DMODEL + h0 * DHEAD + l15;
    const size_t ob1 = (size_t)(b * T_SEQ + qt * 64 + w * 16 + lg * 4) * DMODEL + h1 * DHEAD + l15;
    UNROLL for (int i = 0; i < 4; i++) {
      int src = (lane & 48) + ((lane >> 2) & 12) + i;
      float invA = 1.0f / __shfl(lA, src);
      float invB = 1.0f / __shfl(lB, src);
      UNROLL for (int n = 0; n < 8; n++) {
        AO[ob0 + (size_t)i * DMODEL + n * 16] = (bf16)(oA[n][i] * invA);
        AO[ob1 + (size_t)i * DMODEL + n * 16] = (bf16)(oB[n][i] * invB);
      }
    }
  }
}

extern "C" void kernel_launch(void* const* d_in, const int* in_sizes, int n_in,
                              void* d_out, int out_size, void* d_ws, size_t ws_size,
                              hipStream_t stream) {
  const float* x  = (const float*)d_in[0];
  const float* Wq = (const float*)d_in[1];
  const float* Wk = (const float*)d_in[2];
  const float* Wv = (const float*)d_in[3];
  const float* Wo = (const float*)d_in[4];
  char* ws = (char*)d_ws;
  bf16* xb  = (bf16*)ws;                                             // 4096x2048
  bf16* WT  = (bf16*)(ws + 16777216ull);                             // 3072x2048 (WqT|WkT|WvT)
  bf16* WoT = (bf16*)(ws + 16777216ull + 12582912ull);               // 2048x2048
  bf16* QKV = (bf16*)(ws + 16777216ull + 12582912ull + 8388608ull);  // 4096x3072
  bf16* AO  = (bf16*)(ws + 16777216ull + 12582912ull + 8388608ull + 25165824ull); // 4096x2048
  bf16* Vtg = WT;   // WT is dead after the QKV GEMM; reuse first 4 MB for V^T
  float* out = (float*)d_out;

  k_prep<<<10752, 256, 0, stream>>>(x, Wq, Wk, Wv, Wo, xb, WT, WoT);
  k_gemm<false><<<dim3(32, 24), 256, 0, stream>>>(xb, WT, QKV, 4096, 3072, 2048);
  k_post<<<5632, 256, 0, stream>>>(QKV, Vtg);
  k_flash<<<dim3(32, 16), 256, 0, stream>>>(QKV, Vtg, AO);
  k_gemm<true><<<dim3(32, 16), 256, 0, stream>>>(AO, WoT, out, 4096, 2048, 2048);
}

// Round 9
// 219.085 us; speedup vs baseline: 2.1761x; 1.2158x over previous
//
#include <hip/hip_runtime.h>
#include <stdint.h>

typedef __bf16 bf16;
typedef __bf16 bf16x8 __attribute__((ext_vector_type(8)));
typedef __bf16 bf16x4 __attribute__((ext_vector_type(4)));
typedef float  f32x4  __attribute__((ext_vector_type(4)));

#define T_SEQ  2048
#define NHEAD  16
#define DHEAD  128
#define DMODEL 2048
#define NQKV   3072   // 2048 Q | 512 K | 512 V per row
#define UNROLL _Pragma("unroll")

__device__ __forceinline__ void gload_lds16(const void* g, void* l) {
  __builtin_amdgcn_global_load_lds(
      (const __attribute__((address_space(1))) uint32_t*)g,
      (__attribute__((address_space(3))) uint32_t*)l, 16, 0, 0);
}

// ---------------- fused prep: x cast + 4 weight transposes ----------------
__device__ __forceinline__ void twt_body(const float* __restrict__ W,
                                         bf16* __restrict__ WT, int K, int N,
                                         int bx, int by, float (*t)[65]) {
  int k0 = bx * 64, n0 = by * 64;
  int r4 = threadIdx.x >> 6, c = threadIdx.x & 63;
#pragma unroll
  for (int i = 0; i < 16; i++) {
    int r = i * 4 + r4;
    t[r][c] = W[(size_t)(k0 + r) * N + n0 + c];
  }
  __syncthreads();
#pragma unroll
  for (int i = 0; i < 16; i++) {
    int r = i * 4 + r4;
    WT[(size_t)(n0 + r) * K + k0 + c] = (bf16)t[c][r];
  }
}

__global__ __launch_bounds__(256) void k_prep(const float* __restrict__ x,
                                              const float* __restrict__ Wq,
                                              const float* __restrict__ Wk,
                                              const float* __restrict__ Wv,
                                              const float* __restrict__ Wo,
                                              bf16* __restrict__ xb,
                                              bf16* __restrict__ WT,
                                              bf16* __restrict__ WoT) {
  __shared__ float t[64][65];
  const int blk = blockIdx.x;
  if (blk < 8192) {
    int i = (blk * 256 + threadIdx.x) * 4;
    float4 v = *(const float4*)(x + i);
    bf16x4 o = { (bf16)v.x, (bf16)v.y, (bf16)v.z, (bf16)v.w };
    *(bf16x4*)(xb + i) = o;
  } else if (blk < 9216) {
    int b = blk - 8192;
    twt_body(Wq, WT, 2048, 2048, b & 31, b >> 5, t);
  } else if (blk < 9472) {
    int b = blk - 9216;
    twt_body(Wk, WT + (size_t)2048 * 2048, 2048, 512, b & 31, b >> 5, t);
  } else if (blk < 9728) {
    int b = blk - 9472;
    twt_body(Wv, WT + (size_t)2560 * 2048, 2048, 512, b & 31, b >> 5, t);
  } else {
    int b = blk - 9728;
    twt_body(Wo, WoT, 2048, 2048, b & 31, b >> 5, t);
  }
}

// ---------------- fused post: RoPE (Q,K cols) + V transpose ----------------
__global__ __launch_bounds__(256) void k_post(bf16* __restrict__ QKV,
                                              bf16* __restrict__ Vtg) {
  __shared__ bf16 t[64][65];
  const int blk = blockIdx.x;
  if (blk < 5120) {
    const float L2B = 0.20762050593046007f;  // log2(10000)/64
    int tid = blk * 256 + threadIdx.x;
    int row = tid / 320;
    int c8 = (tid - row * 320) * 8;
    int tt = row & (T_SEQ - 1);
    bf16* p = QKV + (size_t)row * NQKV + c8;
    bf16x8 v = *(const bf16x8*)p;
    int ib = (c8 & 127) >> 1;
    bf16x8 o;
#pragma unroll
    for (int m = 0; m < 4; m++) {
      float inv = exp2f(-(float)(ib + m) * L2B);
      float ang = (float)tt * inv;
      float cs, sn;
      __sincosf(ang, &sn, &cs);
      float x1 = (float)v[2 * m], x2 = (float)v[2 * m + 1];
      o[2 * m]     = (bf16)(x1 * cs - x2 * sn);
      o[2 * m + 1] = (bf16)(x1 * sn + x2 * cs);
    }
    *(bf16x8*)p = o;
  } else {
    int bb = blk - 5120;                 // 512 blocks: 32 x 2 x 8
    int bx = bb & 31, by = (bb >> 5) & 1, g = bb >> 6;
    const int t0 = bx * 64, d0 = by * 64;
    const int b = g >> 2, kvh = g & 3;
    const bf16* src = QKV + (size_t)b * T_SEQ * NQKV + 2560 + kvh * DHEAD;
    bf16* dst = Vtg + ((size_t)(b * 4 + kvh) * 128 + d0) * T_SEQ + t0;
    const int r4 = threadIdx.x >> 6, c = threadIdx.x & 63;
#pragma unroll
    for (int i = 0; i < 16; i++) {
      int r = i * 4 + r4;
      t[r][c] = src[(size_t)(t0 + r) * NQKV + d0 + c];
    }
    __syncthreads();
#pragma unroll
    for (int i = 0; i < 16; i++) {
      int r = i * 4 + r4;
      dst[(size_t)r * T_SEQ + c] = t[c][r];
    }
  }
}

// ---------------- GEMM: 256x256 8-phase counted-vmcnt (T2+T3+T4+T5) ------------
// C[M,N] = A[M,K] * BT[N,K]^T. 512 thr = 8 waves (2Mx4N), per-wave C 128x64.
// LDS 128KB: [buf][A/B][half(128 rows)][128x64 bf16], chunk-XOR p^(row&7) swizzle
// (linear gload_lds dest + inverse-swizzled global source; reads apply same XOR).
// Stage schedule (iteration computes tiles t0=2it from buf0, t1 from buf1):
//  ph1:A0(t1)->b1  ph2:A1(t1)->b1  ph3:B0(t2)->b0  ph4:B1(t2)->b0 [vmcnt(4)]
//  ph5:A0(t2)->b0  ph6:A1(t2)->b0  ph7:B0(t3)->b1  ph8:B1(t3)->b1 [vmcnt(4)]
// B-frags held in regs per K-tile (read phases 1/5); A-frags read per phase.
#define PH(BUF, P, RB, VMW, STAGE) do {                                                   \
    bf16x8 a0k0 = rdA(BUF, 2*(P),     0), a0k1 = rdA(BUF, 2*(P),     1);                  \
    bf16x8 a1k0 = rdA(BUF, 2*(P) + 1, 0), a1k1 = rdA(BUF, 2*(P) + 1, 1);                  \
    if (RB) {                                                                             \
      UNROLL for (int n = 0; n < 4; n++) { b0[n] = rdB(BUF, 0, n); b1[n] = rdB(BUF, 1, n); } \
    }                                                                                     \
    STAGE                                                                                 \
    __builtin_amdgcn_sched_barrier(0);                                                    \
    __builtin_amdgcn_s_barrier();                                                         \
    asm volatile("s_waitcnt lgkmcnt(0)" ::: "memory");                                    \
    __builtin_amdgcn_sched_barrier(0);                                                    \
    __builtin_amdgcn_s_setprio(1);                                                        \
    UNROLL for (int n = 0; n < 4; n++) {                                                  \
      acc[2*(P)][n]   = __builtin_amdgcn_mfma_f32_16x16x32_bf16(a0k0, b0[n], acc[2*(P)][n], 0, 0, 0);     \
      acc[2*(P)][n]   = __builtin_amdgcn_mfma_f32_16x16x32_bf16(a0k1, b1[n], acc[2*(P)][n], 0, 0, 0);     \
      acc[2*(P)+1][n] = __builtin_amdgcn_mfma_f32_16x16x32_bf16(a1k0, b0[n], acc[2*(P)+1][n], 0, 0, 0);   \
      acc[2*(P)+1][n] = __builtin_amdgcn_mfma_f32_16x16x32_bf16(a1k1, b1[n], acc[2*(P)+1][n], 0, 0, 0);   \
    }                                                                                     \
    __builtin_amdgcn_s_setprio(0);                                                        \
    if (VMW) { asm volatile("s_waitcnt vmcnt(4)" ::: "memory"); }                         \
    __builtin_amdgcn_sched_barrier(0);                                                    \
    __builtin_amdgcn_s_barrier();                                                         \
  } while (0)

template<bool F32OUT>
__global__ __launch_bounds__(512) void k_gemm2(const bf16* __restrict__ A,
                                               const bf16* __restrict__ BT,
                                               void* __restrict__ C,
                                               int M, int N, int K) {
  __shared__ __align__(16) bf16 L[2][2][2][8192];   // [buf][A/B][half][128*64]
  const int nwg = gridDim.x * gridDim.y;
  const int orig = blockIdx.y * gridDim.x + blockIdx.x;
  const int tile = (orig & 7) * (nwg >> 3) + (orig >> 3);   // nwg % 8 == 0
  const int m0 = (tile % gridDim.x) * 256, n0 = (tile / gridDim.x) * 256;
  const int tid = threadIdx.x;
  const int lane = tid & 63, w = tid >> 6;
  const int wr = w >> 2, wc = w & 3;
  const int l15 = lane & 15, lg = lane >> 4;
  const int srow = tid >> 3;                       // 0..63
  const int scol = ((tid & 7) ^ (srow & 7)) * 8;   // inverse-swizzled source col
  const int NKT = K >> 6;

  f32x4 acc[8][4] = {};
  bf16x8 b0[4], b1[4];

  auto stA = [&](int buf, int half, int kt) {
    const bf16* g = A + (size_t)(m0 + half * 128 + srow) * K + kt * 64 + scol;
    bf16* lb = &L[buf][0][half][w * 512];
    gload_lds16(g, lb);
    gload_lds16(g + (size_t)64 * K, lb + 4096);
  };
  auto stB = [&](int buf, int half, int kt) {
    const bf16* g = BT + (size_t)(n0 + half * 128 + srow) * K + kt * 64 + scol;
    bf16* lb = &L[buf][1][half][w * 512];
    gload_lds16(g, lb);
    gload_lds16(g + (size_t)64 * K, lb + 4096);
  };
  auto rdA = [&](int buf, int fr, int kk) -> bf16x8 {
    int r = fr * 16 + l15;
    return *(const bf16x8*)((const char*)&L[buf][0][wr][0] + r * 128 +
                            (((kk * 4 + lg) ^ (r & 7)) << 4));
  };
  auto rdB = [&](int buf, int kk, int n) -> bf16x8 {
    int rr = wc * 64 + n * 16 + l15;
    return *(const bf16x8*)((const char*)&L[buf][1][rr >> 7][0] + (rr & 127) * 128 +
                            (((kk * 4 + lg) ^ (rr & 7)) << 4));
  };

  // prologue: tile0 A+B -> buf0, tile1 B -> buf1 (A(t1) staged in ph1/ph2)
  stA(0, 0, 0); stA(0, 1, 0);
  stB(0, 0, 0); stB(0, 1, 0);
  stB(1, 0, 1); stB(1, 1, 1);
  asm volatile("s_waitcnt vmcnt(4)" ::: "memory");   // tile0 landed; tile1 B in flight
  __builtin_amdgcn_sched_barrier(0);
  __builtin_amdgcn_s_barrier();

  for (int it = 0; it < (NKT >> 1); ++it) {
    const int t1 = 2 * it + 1;
    const int t2 = (t1 + 1 < NKT) ? t1 + 1 : NKT - 1;  // clamped tail stages write
    const int t3 = (t1 + 2 < NKT) ? t1 + 2 : NKT - 1;  // freed/identical regions
    PH(0, 0, 1, 0, stA(1, 0, t1););
    PH(0, 1, 0, 0, stA(1, 1, t1););
    PH(0, 2, 0, 0, stB(0, 0, t2););
    PH(0, 3, 0, 1, stB(0, 1, t2););
    PH(1, 0, 1, 0, stA(0, 0, t2););
    PH(1, 1, 0, 0, stA(0, 1, t2););
    PH(1, 2, 0, 0, stB(1, 0, t3););
    PH(1, 3, 0, 1, stB(1, 1, t3););
  }

  const int r0 = m0 + wr * 128 + lg * 4;
  const int c0 = n0 + wc * 64 + l15;
  UNROLL for (int m = 0; m < 8; m++)
    UNROLL for (int n = 0; n < 4; n++)
      UNROLL for (int i = 0; i < 4; i++) {
        size_t idx = (size_t)(r0 + m * 16 + i) * N + (c0 + n * 16);
        if (F32OUT) ((float*)C)[idx] = acc[m][n][i];
        else        ((bf16*)C)[idx]  = (bf16)acc[m][n][i];
      }
}

// ---------------- flash attention (causal, GQA), head-paired, shared-operand ----
#define COMPUTE2(kt, cur) do {                                                            \
    f32x4 sA_[4] = {}, sB_[4] = {};                                                       \
    const char* ks_ = (const char*)Ks[cur];                                               \
    __builtin_amdgcn_s_setprio(1);                                                        \
    UNROLL for (int kk = 0; kk < 4; kk++)                                                 \
      UNROLL for (int n = 0; n < 4; n++) {                                                \
        int row_ = n * 16 + l15;                                                          \
        int cb_ = (kk * 64 + lg * 16) ^ ((row_ & 7) << 4);                                \
        bf16x8 kf_ = *(const bf16x8*)(ks_ + row_ * 256 + cb_);                            \
        sA_[n] = __builtin_amdgcn_mfma_f32_16x16x32_bf16(kf_, qA[kk], sA_[n], 0, 0, 0);   \
        sB_[n] = __builtin_amdgcn_mfma_f32_16x16x32_bf16(kf_, qB[kk], sB_[n], 0, 0, 0);   \
      }                                                                                   \
    __builtin_amdgcn_s_setprio(0);                                                        \
    float vmA_ = -1e30f, vmB_ = -1e30f;                                                   \
    if ((kt) == qt) {                                                                     \
      UNROLL for (int n = 0; n < 4; n++)                                                  \
        UNROLL for (int i = 0; i < 4; i++) {                                              \
          if ((kt) * 64 + n * 16 + lg * 4 + i > qglob) {                                  \
            sA_[n][i] = -1e30f; sB_[n][i] = -1e30f;                                       \
          }                                                                               \
          vmA_ = fmaxf(vmA_, sA_[n][i]);                                                  \
          vmB_ = fmaxf(vmB_, sB_[n][i]);                                                  \
        }                                                                                 \
    } else {                                                                              \
      UNROLL for (int n = 0; n < 4; n++)                                                  \
        UNROLL for (int i = 0; i < 4; i++) {                                              \
          vmA_ = fmaxf(vmA_, sA_[n][i]);                                                  \
          vmB_ = fmaxf(vmB_, sB_[n][i]);                                                  \
        }                                                                                 \
    }                                                                                     \
    vmA_ = fmaxf(vmA_, __shfl_xor(vmA_, 16));                                             \
    vmA_ = fmaxf(vmA_, __shfl_xor(vmA_, 32));                                             \
    vmB_ = fmaxf(vmB_, __shfl_xor(vmB_, 16));                                             \
    vmB_ = fmaxf(vmB_, __shfl_xor(vmB_, 32));                                             \
    if (!__all((vmA_ <= mA + 8.0f) && (vmB_ <= mB + 8.0f))) {                             \
      float mnA_ = fmaxf(mA, vmA_), mnB_ = fmaxf(mB, vmB_);                               \
      float alA_ = __builtin_amdgcn_exp2f(mA - mnA_);                                     \
      float alB_ = __builtin_amdgcn_exp2f(mB - mnB_);                                     \
      mA = mnA_; mB = mnB_;                                                               \
      lA *= alA_; lB *= alB_;                                                             \
      UNROLL for (int i = 0; i < 4; i++) {                                                \
        int src_ = (lane & 48) + ((lane >> 2) & 12) + i;                                  \
        float aA_ = __shfl(alA_, src_);                                                   \
        float aB_ = __shfl(alB_, src_);                                                   \
        UNROLL for (int n = 0; n < 8; n++) { oA[n][i] *= aA_; oB[n][i] *= aB_; }          \
      }                                                                                   \
    }                                                                                     \
    bf16x8 paA0_, paA1_, paB0_, paB1_;                                                    \
    {                                                                                     \
      float rs_ = 0.f;                                                                    \
      UNROLL for (int n = 0; n < 4; n++) {                                                \
        bf16x4 pk_;                                                                       \
        UNROLL for (int i = 0; i < 4; i++) {                                              \
          float pv_ = __builtin_amdgcn_exp2f(sA_[n][i] - mA);                             \
          rs_ += pv_;                                                                     \
          pk_[i] = (bf16)pv_;                                                             \
        }                                                                                 \
        *(bf16x4*)(&Ps[w][l15][n * 16 + lg * 4]) = pk_;                                   \
      }                                                                                   \
      rs_ += __shfl_xor(rs_, 16);                                                         \
      rs_ += __shfl_xor(rs_, 32);                                                         \
      lA += rs_;                                                                          \
      paA0_ = *(const bf16x8*)(&Ps[w][l15][lg * 8]);                                      \
      paA1_ = *(const bf16x8*)(&Ps[w][l15][32 + lg * 8]);                                 \
    }                                                                                     \
    {                                                                                     \
      float rs_ = 0.f;                                                                    \
      UNROLL for (int n = 0; n < 4; n++) {                                                \
        bf16x4 pk_;                                                                       \
        UNROLL for (int i = 0; i < 4; i++) {                                              \
          float pv_ = __builtin_amdgcn_exp2f(sB_[n][i] - mB);                             \
          rs_ += pv_;                                                                     \
          pk_[i] = (bf16)pv_;                                                             \
        }                                                                                 \
        *(bf16x4*)(&Ps[w][l15][n * 16 + lg * 4]) = pk_;                                   \
      }                                                                                   \
      rs_ += __shfl_xor(rs_, 16);                                                         \
      rs_ += __shfl_xor(rs_, 32);                                                         \
      lB += rs_;                                                                          \
      paB0_ = *(const bf16x8*)(&Ps[w][l15][lg * 8]);                                      \
      paB1_ = *(const bf16x8*)(&Ps[w][l15][32 + lg * 8]);                                 \
    }                                                                                     \
    const char* vs_ = (const char*)Vs[cur];                                               \
    __builtin_amdgcn_s_setprio(1);                                                        \
    UNROLL for (int n = 0; n < 8; n++) {                                                  \
      int d_ = n * 16 + l15;                                                              \
      bf16x8 vf0_ = *(const bf16x8*)(vs_ + d_ * 128 + (((lg) ^ (d_ & 7)) << 4));          \
      oA[n] = __builtin_amdgcn_mfma_f32_16x16x32_bf16(paA0_, vf0_, oA[n], 0, 0, 0);       \
      oB[n] = __builtin_amdgcn_mfma_f32_16x16x32_bf16(paB0_, vf0_, oB[n], 0, 0, 0);       \
      bf16x8 vf1_ = *(const bf16x8*)(vs_ + d_ * 128 + (((4 + lg) ^ (d_ & 7)) << 4));      \
      oA[n] = __builtin_amdgcn_mfma_f32_16x16x32_bf16(paA1_, vf1_, oA[n], 0, 0, 0);       \
      oB[n] = __builtin_amdgcn_mfma_f32_16x16x32_bf16(paB1_, vf1_, oB[n], 0, 0, 0);       \
    }                                                                                     \
    __builtin_amdgcn_s_setprio(0);                                                        \
  } while (0)

__global__ __launch_bounds__(256) void k_flash(const bf16* __restrict__ QKV,
                                               const bf16* __restrict__ Vtg,
                                               bf16* __restrict__ AO) {
  __shared__ __align__(16) bf16 Ks[2][64 * 128];   // [kv row]*256B, chunk XOR (row&7)
  __shared__ __align__(16) bf16 Vs[2][128 * 64];   // [d row]*128B,  chunk XOR (d&7)
  __shared__ __align__(16) bf16 Ps[4][16][72];     // [q][kv], 144B rows (16B-aligned)
  const int orig = blockIdx.y * 32 + blockIdx.x;
  const int fin  = ((orig & 7) << 6) | (orig >> 3);
  const int bhp  = fin >> 5;                 // b*8 + kvh*2 + hp
  const int qt   = 31 - (fin & 31);
  const int b = bhp >> 3, kvh = (bhp >> 1) & 3, hp = bhp & 1;
  const int h0 = kvh * 4 + hp * 2, h1 = h0 + 1;
  const int tid = threadIdx.x, lane = tid & 63, w = tid >> 6;
  const int l15 = lane & 15, lg = lane >> 4;
  const int qglob = qt * 64 + w * 16 + l15;
  const float qs = 0.12753102f;              // (1/sqrt(128)) * log2(e)

  bf16x8 qA[4], qB[4];
  {
    const size_t qoA = (size_t)(b * T_SEQ + qt * 64 + w * 16 + l15) * NQKV + h0 * DHEAD;
    const size_t qoB = (size_t)(b * T_SEQ + qt * 64 + w * 16 + l15) * NQKV + h1 * DHEAD;
    UNROLL for (int kk = 0; kk < 4; kk++) {
      bf16x8 a = *(const bf16x8*)(QKV + qoA + kk * 32 + lg * 8);
      bf16x8 bb = *(const bf16x8*)(QKV + qoB + kk * 32 + lg * 8);
      UNROLL for (int j = 0; j < 8; j++) {
        a[j] = (bf16)((float)a[j] * qs);
        bb[j] = (bf16)((float)bb[j] * qs);
      }
      qA[kk] = a; qB[kk] = bb;
    }
  }

  f32x4 oA[8] = {}, oB[8] = {};
  float mA = -1e30f, mB = -1e30f, lA = 0.f, lB = 0.f;

  const bf16* Kbase = QKV + (size_t)b * T_SEQ * NQKV + DMODEL + kvh * DHEAD;
  const bf16* Vbase = Vtg + (size_t)(b * 4 + kvh) * 128 * T_SEQ;

  auto issueK = [&](int buf, int kt) {
    UNROLL for (int i = 0; i < 4; i++) {
      int row = w * 16 + i * 4 + lg;
      int col = (l15 ^ (row & 7)) * 8;
      gload_lds16(Kbase + (size_t)(kt * 64 + row) * NQKV + col,
                  Ks[buf] + (w * 4 + i) * 512);
    }
  };
  auto issueV = [&](int buf, int kt) {
    UNROLL for (int i = 0; i < 4; i++) {
      int d = (w * 4 + i) * 8 + (lane >> 3);
      int u = lane & 7;
      gload_lds16(Vbase + (size_t)d * T_SEQ + kt * 64 + ((u ^ (d & 7)) * 8),
                  Vs[buf] + (w * 4 + i) * 512);
    }
  };

  issueK(0, 0);
  issueV(0, 0);
  __syncthreads();

  const int NT = qt + 1;
  for (int kt = 0; kt < NT; kt++) {
    const int cur = kt & 1, nxt = cur ^ 1;
    if (kt + 1 < NT) { issueK(nxt, kt + 1); issueV(nxt, kt + 1); }
    COMPUTE2(kt, cur);
    __syncthreads();
  }

  {
    const size_t ob0 = (size_t)(b * T_SEQ + qt * 64 + w * 16 + lg * 4) * DMODEL + h0 * DHEAD + l15;
    const size_t ob1 = (size_t)(b * T_SEQ + qt * 64 + w * 16 + lg * 4) * DMODEL + h1 * DHEAD + l15;
    UNROLL for (int i = 0; i < 4; i++) {
      int src = (lane & 48) + ((lane >> 2) & 12) + i;
      float invA = 1.0f / __shfl(lA, src);
      float invB = 1.0f / __shfl(lB, src);
      UNROLL for (int n = 0; n < 8; n++) {
        AO[ob0 + (size_t)i * DMODEL + n * 16] = (bf16)(oA[n][i] * invA);
        AO[ob1 + (size_t)i * DMODEL + n * 16] = (bf16)(oB[n][i] * invB);
      }
    }
  }
}

extern "C" void kernel_launch(void* const* d_in, const int* in_sizes, int n_in,
                              void* d_out, int out_size, void* d_ws, size_t ws_size,
                              hipStream_t stream) {
  const float* x  = (const float*)d_in[0];
  const float* Wq = (const float*)d_in[1];
  const float* Wk = (const float*)d_in[2];
  const float* Wv = (const float*)d_in[3];
  const float* Wo = (const float*)d_in[4];
  char* ws = (char*)d_ws;
  bf16* xb  = (bf16*)ws;                                             // 4096x2048
  bf16* WT  = (bf16*)(ws + 16777216ull);                             // 3072x2048 (WqT|WkT|WvT)
  bf16* WoT = (bf16*)(ws + 16777216ull + 12582912ull);               // 2048x2048
  bf16* QKV = (bf16*)(ws + 16777216ull + 12582912ull + 8388608ull);  // 4096x3072
  bf16* AO  = (bf16*)(ws + 16777216ull + 12582912ull + 8388608ull + 25165824ull); // 4096x2048
  bf16* Vtg = WT;   // WT is dead after the QKV GEMM; reuse first 4 MB for V^T
  float* out = (float*)d_out;

  k_prep<<<10752, 256, 0, stream>>>(x, Wq, Wk, Wv, Wo, xb, WT, WoT);
  k_gemm2<false><<<dim3(16, 12), 512, 0, stream>>>(xb, WT, QKV, 4096, 3072, 2048);
  k_post<<<5632, 256, 0, stream>>>(QKV, Vtg);
  k_flash<<<dim3(32, 16), 256, 0, stream>>>(QKV, Vtg, AO);
  k_gemm2<true><<<dim3(16, 8), 512, 0, stream>>>(AO, WoT, out, 4096, 2048, 2048);
}